// Round 1
// 670.108 us; speedup vs baseline: 1.0736x; 1.0736x over previous
//
#include <hip/hip_runtime.h>

typedef __attribute__((ext_vector_type(4))) float f32x4;
typedef __attribute__((ext_vector_type(8))) short short8;
typedef __attribute__((ext_vector_type(8))) __bf16 bf16x8;
typedef __attribute__((ext_vector_type(4))) unsigned int u32x4;
typedef __attribute__((ext_vector_type(4))) unsigned short u16x4;
typedef unsigned short u16;
typedef unsigned int u32;

#define NB 2
#define S_LEN 4096
#define NHD 8
#define HID 512

__device__ __forceinline__ u16 f2bf(float f) {
  u32 u = __builtin_bit_cast(u32, f);
  u += 0x7fffu + ((u >> 16) & 1u);   // round-to-nearest-even
  return (u16)(u >> 16);
}

// MFMA wrapper hedged over the two plausible builtin signatures (V8s vs V8y).
template <typename V>
static __device__ __forceinline__ auto mfma_imp(V a, V b, f32x4 c, int)
    -> decltype(__builtin_amdgcn_mfma_f32_16x16x32_bf16(a, b, c, 0, 0, 0)) {
  return __builtin_amdgcn_mfma_f32_16x16x32_bf16(a, b, c, 0, 0, 0);
}
template <typename V>
static __device__ __forceinline__ f32x4 mfma_imp(V a, V b, f32x4 c, long) {
  return __builtin_amdgcn_mfma_f32_16x16x32_bf16(
      __builtin_bit_cast(bf16x8, a), __builtin_bit_cast(bf16x8, b), c, 0, 0, 0);
}
static __device__ __forceinline__ f32x4 mfma_bf16(short8 a, short8 b, f32x4 c) {
  return mfma_imp(a, b, c, 0);
}

// ---------------------------------------------------------------------------
// Projection GEMM: C[i][j] = sum_k X[i][k] * W[j][k] + bias[j], scaled, ->bf16
// out layout: transposeOut==0 : [(b*8+h)][s][64]   (Q, K)
//             transposeOut==1 : [(b*8+h)][64][s]   (V^T, so PV B-operand is contiguous)
// ---------------------------------------------------------------------------
__global__ __launch_bounds__(256, 2) void proj_kernel(
    const float* __restrict__ X, const float* __restrict__ W,
    const float* __restrict__ bias, u16* __restrict__ out,
    const int transposeOut, const float scale)
{
  __shared__ u16 Al[128 * 64];
  __shared__ u16 Bl[128 * 64];
  const int tid = threadIdx.x;
  const int lane = tid & 63;
  const int wid = tid >> 6;
  const int wr = (wid >> 1) << 6;
  const int wc = (wid & 1) << 6;
  const int bm = blockIdx.x << 7;
  const int bn = blockIdx.y << 7;

  f32x4 acc[4][4] = {};

#pragma unroll 1
  for (int k0 = 0; k0 < HID; k0 += 64) {
    __syncthreads();
#pragma unroll
    for (int i = 0; i < 4; ++i) {
      const int idx = i * 256 + tid;
      const int row = idx >> 3;     // 8 chunks of 8 elems per 64-wide row
      const int c = idx & 7;
      const int off = (row * 128 + c * 16) ^ ((row & 7) << 4);
      const float* ga = X + (size_t)(bm + row) * HID + k0 + c * 8;
      f32x4 a0 = *(const f32x4*)ga;
      f32x4 a1 = *(const f32x4*)(ga + 4);
      short8 pa;
      pa[0] = (short)f2bf(a0[0]); pa[1] = (short)f2bf(a0[1]);
      pa[2] = (short)f2bf(a0[2]); pa[3] = (short)f2bf(a0[3]);
      pa[4] = (short)f2bf(a1[0]); pa[5] = (short)f2bf(a1[1]);
      pa[6] = (short)f2bf(a1[2]); pa[7] = (short)f2bf(a1[3]);
      *(short8*)((char*)Al + off) = pa;
      const float* gb = W + (size_t)(bn + row) * HID + k0 + c * 8;
      f32x4 b0 = *(const f32x4*)gb;
      f32x4 b1 = *(const f32x4*)(gb + 4);
      short8 pb;
      pb[0] = (short)f2bf(b0[0]); pb[1] = (short)f2bf(b0[1]);
      pb[2] = (short)f2bf(b0[2]); pb[3] = (short)f2bf(b0[3]);
      pb[4] = (short)f2bf(b1[0]); pb[5] = (short)f2bf(b1[1]);
      pb[6] = (short)f2bf(b1[2]); pb[7] = (short)f2bf(b1[3]);
      *(short8*)((char*)Bl + off) = pb;
    }
    __syncthreads();
#pragma unroll
    for (int ks = 0; ks < 2; ++ks) {
      const int koffb = (ks * 32 + ((lane >> 4) << 3)) * 2;
      short8 af[4], bfr[4];
#pragma unroll
      for (int m = 0; m < 4; ++m) {
        const int row = wr + m * 16 + (lane & 15);
        af[m] = *(const short8*)((const char*)Al + ((row * 128 + koffb) ^ ((row & 7) << 4)));
      }
#pragma unroll
      for (int n = 0; n < 4; ++n) {
        const int row = wc + n * 16 + (lane & 15);
        bfr[n] = *(const short8*)((const char*)Bl + ((row * 128 + koffb) ^ ((row & 7) << 4)));
      }
#pragma unroll
      for (int m = 0; m < 4; ++m)
#pragma unroll
        for (int n = 0; n < 4; ++n)
          acc[m][n] = mfma_bf16(af[m], bfr[n], acc[m][n]);
    }
  }

#pragma unroll
  for (int n = 0; n < 4; ++n) {
    const int j = bn + wc + n * 16 + (lane & 15);
    const float bj = bias[j];
    const int h = j >> 6, d = j & 63;
#pragma unroll
    for (int m = 0; m < 4; ++m) {
      const int rbase = bm + wr + m * 16 + ((lane >> 4) << 2);
      const int b = rbase >> 12;
      const int s = rbase & (S_LEN - 1);
      if (!transposeOut) {
#pragma unroll
        for (int i = 0; i < 4; ++i) {
          const float v = (acc[m][n][i] + bj) * scale;
          out[(((size_t)(b * NHD + h) * S_LEN + (s + i)) << 6) + d] = f2bf(v);
        }
      } else {
        u16x4 pk;
#pragma unroll
        for (int i = 0; i < 4; ++i) pk[i] = f2bf((acc[m][n][i] + bj) * scale);
        *(u16x4*)(out + (((size_t)(b * NHD + h) * 64 + d) << 12) + s) = pk;
      }
    }
  }
}

// ---------------------------------------------------------------------------
// Fused attention, barrier-free main loops.
// One WG per (b*8+h, 128-row q-tile); 4 waves x 32 q-rows.
// K/V/Q MFMA fragments are 16 contiguous bytes of one row -> loaded DIRECTLY
// from global (L2-resident: K+V per head = 1 MB; XCD swizzle keeps 2 heads
// per XCD L2). No LDS staging of K/V/Q, hence no __syncthreads() in the kt
// loops: the nontemporal W-store stream is never drained by a barrier and
// runs at HBM rate while MFMA/exp/L2-loads overlap underneath.
// Only LDS use: wave-private P redistribution buffer (same-wave RAW).
// Swapped QK^T: S^T = K·Q^T so C-frag holds 4 consecutive KEYS per lane.
// Pass A: softmax denominators. Pass B: recompute S, write normalized W
// (fp32, nontemporal), accumulate O = P·V.
// ---------------------------------------------------------------------------
__global__ __launch_bounds__(256, 2) void attn_kernel(
    const u16* __restrict__ Qp, const u16* __restrict__ Kp,
    const u16* __restrict__ Vt, const unsigned char* __restrict__ mask,
    float* __restrict__ outO, float* __restrict__ outW)
{
  __shared__ u16 Pl[4][32 * 128];   // per-wave normalized P (bf16, swizzled)
  __shared__ u32 anyMaskSh;

  const int tid = threadIdx.x;
  const int lane = tid & 63;
  const int wid = tid >> 6;
  const int lr = lane & 15;         // row within 16
  const int lg = lane >> 4;         // lane group 0..3

  // XCD-bijective swizzle: 512 blocks round-robin over 8 XCDs; give each XCD
  // a contiguous 64-block chunk = 2 heads (K+V = 2 MB fits its 4 MB L2).
  const int bid = blockIdx.x;
  const int swz = (bid & 7) * 64 + (bid >> 3);
  const int bh = swz >> 5;          // b*8 + h
  const int q0 = (swz & 31) << 7;
  const int b = bh >> 3;
  const int h = bh & 7;

  if (tid == 0) anyMaskSh = 0u;
  __syncthreads();
  {
    u32x4 mv = *(const u32x4*)(mask + (size_t)b * S_LEN + tid * 16);
    if (mv[0] | mv[1] | mv[2] | mv[3]) atomicOr(&anyMaskSh, 1u);
  }
  __syncthreads();
  const bool anyMask = (anyMaskSh != 0u);

  // Q fragments (MFMA B operand) straight from global — constant all kernel
  short8 bq[2][2];
#pragma unroll
  for (int cb = 0; cb < 2; ++cb)
#pragma unroll
    for (int ks = 0; ks < 2; ++ks)
      bq[cb][ks] = *(const short8*)(
          Qp + (((size_t)bh * S_LEN + q0 + (wid << 5) + (cb << 4) + lr) << 6)
             + ks * 32 + lg * 8);

  // per-lane K fragment base: row (lane&15) of the head, elem offset lg*8
  const u16* kbase = Kp + (((size_t)bh * S_LEN + lr) << 6) + lg * 8;
  const unsigned char* mbase = mask + (size_t)b * S_LEN + (lg << 2);

  // ---------------- pass A: softmax denominators ----------------
  float lsum[2] = {0.f, 0.f};
#pragma unroll 1
  for (int kt = 0; kt < 32; ++kt) {
    const u16* kp = kbase + ((size_t)kt << 13);   // + kt*128 rows * 64
#pragma unroll
    for (int rb = 0; rb < 8; ++rb) {
      short8 ak0 = *(const short8*)(kp + (rb << 10));
      short8 ak1 = *(const short8*)(kp + (rb << 10) + 32);
      u32 mw = 0u;
      if (anyMask) mw = *(const u32*)(mbase + (kt << 7) + (rb << 4));
#pragma unroll
      for (int cb = 0; cb < 2; ++cb) {
        f32x4 sv = {};
        sv = mfma_bf16(ak0, bq[cb][0], sv);
        sv = mfma_bf16(ak1, bq[cb][1], sv);
        float p0 = __expf(sv[0]);
        float p1 = __expf(sv[1]);
        float p2 = __expf(sv[2]);
        float p3 = __expf(sv[3]);
        if (mw) {
          if (mw & 0x000000FFu) p0 = 0.f;
          if (mw & 0x0000FF00u) p1 = 0.f;
          if (mw & 0x00FF0000u) p2 = 0.f;
          if (mw & 0xFF000000u) p3 = 0.f;
        }
        lsum[cb] += (p0 + p1) + (p2 + p3);
      }
    }
  }
  float inv[2];
#pragma unroll
  for (int cb = 0; cb < 2; ++cb) {
    float t = lsum[cb];
    t += __shfl_xor(t, 16);
    t += __shfl_xor(t, 32);
    inv[cb] = 1.0f / t;
  }

  // ---------------- pass B: weights out + O = P·V ----------------
  f32x4 oacc[2][4] = {};
#pragma unroll 1
  for (int kt = 0; kt < 32; ++kt) {
    const u16* kp = kbase + ((size_t)kt << 13);
    float* wbase = outW + (((size_t)bh * S_LEN + q0 + (wid << 5) + lr) << 12)
                 + (kt << 7) + (lg << 2);
#pragma unroll
    for (int rb = 0; rb < 8; ++rb) {
      short8 ak0 = *(const short8*)(kp + (rb << 10));
      short8 ak1 = *(const short8*)(kp + (rb << 10) + 32);
      u32 mw = 0u;
      if (anyMask) mw = *(const u32*)(mbase + (kt << 7) + (rb << 4));
#pragma unroll
      for (int cb = 0; cb < 2; ++cb) {
        f32x4 sv = {};
        sv = mfma_bf16(ak0, bq[cb][0], sv);
        sv = mfma_bf16(ak1, bq[cb][1], sv);
        float p0 = __expf(sv[0]) * inv[cb];
        float p1 = __expf(sv[1]) * inv[cb];
        float p2 = __expf(sv[2]) * inv[cb];
        float p3 = __expf(sv[3]) * inv[cb];
        if (mw) {
          if (mw & 0x000000FFu) p0 = 0.f;
          if (mw & 0x0000FF00u) p1 = 0.f;
          if (mw & 0x00FF0000u) p2 = 0.f;
          if (mw & 0xFF000000u) p3 = 0.f;
        }
        f32x4 wv; wv[0] = p0; wv[1] = p1; wv[2] = p2; wv[3] = p3;
        __builtin_nontemporal_store(wv,
            (f32x4*)(wbase + ((size_t)cb << 16) + (rb << 4)));
        u16x4 pk;
        pk[0] = f2bf(p0); pk[1] = f2bf(p1); pk[2] = f2bf(p2); pk[3] = f2bf(p3);
        const int ql = (cb << 4) + lr;
        *(u16x4*)((char*)Pl[wid] +
            ((ql * 256 + (rb << 5) + (lg << 3)) ^ ((ql & 7) << 4))) = pk;
      }
    }
    // PV: P is wave-private (same-wave RAW on LDS — no barrier needed);
    // V^T fragments straight from global (L2-hot).
#pragma unroll
    for (int kk = 0; kk < 4; ++kk) {
      short8 ap[2];
#pragma unroll
      for (int rq = 0; rq < 2; ++rq) {
        const int qrow = (rq << 4) + lr;
        ap[rq] = *(const short8*)((const char*)Pl[wid] +
            ((qrow * 256 + (kk << 6) + (lg << 4)) ^ ((qrow & 7) << 4)));
      }
#pragma unroll
      for (int cd = 0; cd < 4; ++cd) {
        const u16* vp = Vt + (((size_t)bh * 64 + (cd << 4) + lr) << 12)
                      + (kt << 7) + (kk << 5) + lg * 8;
        short8 bv = *(const short8*)vp;
        oacc[0][cd] = mfma_bf16(ap[0], bv, oacc[0][cd]);
        oacc[1][cd] = mfma_bf16(ap[1], bv, oacc[1][cd]);
      }
    }
  }

  // epilogue: O
#pragma unroll
  for (int rq = 0; rq < 2; ++rq)
#pragma unroll
    for (int cd = 0; cd < 4; ++cd)
#pragma unroll
      for (int i = 0; i < 4; ++i) {
        const int q = q0 + (wid << 5) + (rq << 4) + (lg << 2) + i;
        const int d = (cd << 4) + lr;
        __builtin_nontemporal_store(oacc[rq][cd][i],
            outO + (((size_t)b * S_LEN + q) << 9) + h * 64 + d);
      }
}

extern "C" void kernel_launch(void* const* d_in, const int* in_sizes, int n_in,
                              void* d_out, int out_size, void* d_ws, size_t ws_size,
                              hipStream_t stream) {
  (void)in_sizes; (void)n_in; (void)out_size; (void)ws_size;
  const float* query = (const float*)d_in[0];
  const float* key_i = (const float*)d_in[1];
  const float* value = (const float*)d_in[2];
  const unsigned char* kpm = (const unsigned char*)d_in[3];
  const float* Wq = (const float*)d_in[4];
  const float* bq_ = (const float*)d_in[5];
  const float* Wk = (const float*)d_in[6];
  const float* bk_ = (const float*)d_in[7];
  const float* Wv = (const float*)d_in[8];
  const float* bv_ = (const float*)d_in[9];

  u16* Qp = (u16*)d_ws;                                  // [16][4096][64] bf16
  u16* Kp = Qp + (size_t)NB * NHD * S_LEN * 64;          // [16][4096][64] bf16
  u16* Vt = Kp + (size_t)NB * NHD * S_LEN * 64;          // [16][64][4096] bf16

  float* outO = (float*)d_out;
  float* outW = outO + (size_t)NB * S_LEN * HID;

  dim3 pg(64, 4), pb(256);
  // scale 1/sqrt(64) folded into Q projection
  proj_kernel<<<pg, pb, 0, stream>>>(query, Wq, bq_, Qp, 0, 0.125f);
  proj_kernel<<<pg, pb, 0, stream>>>(key_i, Wk, bk_, Kp, 0, 1.0f);
  proj_kernel<<<pg, pb, 0, stream>>>(value, Wv, bv_, Vt, 1, 1.0f);
  attn_kernel<<<dim3(512), dim3(256), 0, stream>>>(Qp, Kp, Vt, kpm, outO, outW);
}